// Round 7
// baseline (38.441 us; speedup 1.0000x reference)
//
#include <hip/hip_runtime.h>

#define B_ 1024
#define N_ 20000
#define M_ 10000
#define K_ 8
#define OBS_W_ 200
#define TPB 1024
#define HALF_M (M_ / 2)

constexpr float EPS_   = 1e-6f;
constexpr float LN2_   = 0.69314718055994530942f;
constexpr float LOG2E_ = 1.4426950408889634f;
constexpr float QSCALE   = 127.0f;
constexpr float QINV     = 1.0f / 127.0f;
constexpr float QBIASINV = -128.0f / 127.0f;

// tanh(x/2) = 1 - 2/(exp(x)+1), via hardware v_exp_f32 / v_rcp_f32.
__device__ __forceinline__ float tanh_half_fast(float x) {
    float e = __builtin_amdgcn_exp2f(x * LOG2E_);
    return 1.0f - 2.0f * __builtin_amdgcn_rcpf(e + 1.0f);
}

__device__ __forceinline__ float bce_log2(float p, float y) {
    // ln2 - log1p((1-2y)*p) accumulated as log2; caller applies LN2*(cnt-acc).
    p = fminf(fmaxf(p, -1.0f + EPS_), 1.0f - EPS_);
    float w = fmaf(1.0f - 2.0f * y, p, 1.0f);
    return __builtin_amdgcn_logf(w);   // log2(w)
}

// int8 symmetric quant: q = rint(t*127)+128 in [1,255]; t in (-1,1).
__device__ __forceinline__ unsigned int quant8(float t) {
    return (unsigned int)(int)rintf(fmaf(t, QSCALE, 128.0f));
}
__device__ __forceinline__ unsigned int pack4_q8(float a, float b, float c, float d) {
    return quant8(a) | (quant8(b) << 8) | (quant8(c) << 16) | (quant8(d) << 24);
}
// decode byte k of word g -> float t; lowers to v_cvt_f32_ubyteN + v_fma.
__device__ __forceinline__ float dec8(unsigned int g, int k) {
    float u = (float)((g >> (8 * k)) & 0xffu);
    return fmaf(u, QINV, QBIASINV);
}

// ---- int8: 4 rows per uint32, 80 KB LDS, 2 blocks/CU, checks h-split -------
// Pair (g, h): rows 4g..4g+3; h=0 -> checks [0,M/2) + obs part; h=1 -> rest.
// blockIdx mapping g = bid&255, h = bid>>8 keeps the pair on the same XCD.
template <bool ATOMIC>
__global__ __launch_bounds__(TPB) void decode_loss_q8(
    const float* __restrict__ llrs,
    const float* __restrict__ syndromes,
    const float* __restrict__ observables,
    const int*   __restrict__ chk_cols,
    const int*   __restrict__ obs_cols,
    float* __restrict__ part)
{
    extern __shared__ char smem_raw[];
    unsigned int* t8 = reinterpret_cast<unsigned int*>(smem_raw);
    __shared__ float red[TPB / 64];

    const int g   = blockIdx.x & 255;
    const int h   = blockIdx.x >> 8;
    const int b0  = 4 * g;
    const int tid = threadIdx.x;

    // Stage: t8[n] = bytes {q(r0), q(r1), q(r2), q(r3)}.
    const float4* r0 = reinterpret_cast<const float4*>(llrs + (size_t)(b0 + 0) * N_);
    const float4* r1 = reinterpret_cast<const float4*>(llrs + (size_t)(b0 + 1) * N_);
    const float4* r2 = reinterpret_cast<const float4*>(llrs + (size_t)(b0 + 2) * N_);
    const float4* r3 = reinterpret_cast<const float4*>(llrs + (size_t)(b0 + 3) * N_);
    for (int i = tid; i < N_ / 4; i += TPB) {
        float4 a = r0[i], b = r1[i], c = r2[i], d = r3[i];
        int4 w;
        w.x = (int)pack4_q8(tanh_half_fast(a.x), tanh_half_fast(b.x),
                            tanh_half_fast(c.x), tanh_half_fast(d.x));
        w.y = (int)pack4_q8(tanh_half_fast(a.y), tanh_half_fast(b.y),
                            tanh_half_fast(c.y), tanh_half_fast(d.y));
        w.z = (int)pack4_q8(tanh_half_fast(a.z), tanh_half_fast(b.z),
                            tanh_half_fast(c.z), tanh_half_fast(d.z));
        w.w = (int)pack4_q8(tanh_half_fast(a.w), tanh_half_fast(b.w),
                            tanh_half_fast(c.w), tanh_half_fast(d.w));
        *reinterpret_cast<int4*>(&t8[4 * i]) = w;
    }
    __syncthreads();

    // Check part: this block handles checks [h*M/2, (h+1)*M/2).
    float acc = 0.0f;
    int   cnt = 0;
    const int mbase = h * HALF_M;
    const float* syn0 = syndromes + (size_t)(b0 + 0) * M_ + mbase;
    const float* syn1 = syndromes + (size_t)(b0 + 1) * M_ + mbase;
    const float* syn2 = syndromes + (size_t)(b0 + 2) * M_ + mbase;
    const float* syn3 = syndromes + (size_t)(b0 + 3) * M_ + mbase;
    const int4*  cc   = reinterpret_cast<const int4*>(chk_cols) + 2 * mbase;
    for (int m = tid; m < HALF_M; m += TPB) {
        int4 c0 = cc[2 * m];
        int4 c1 = cc[2 * m + 1];
        unsigned int g0 = t8[c0.x], g1 = t8[c0.y], g2 = t8[c0.z], g3 = t8[c0.w];
        unsigned int g4 = t8[c1.x], g5 = t8[c1.y], g6 = t8[c1.z], g7 = t8[c1.w];
        float p0 = dec8(g0, 0), p1 = dec8(g0, 1), p2 = dec8(g0, 2), p3 = dec8(g0, 3);
        p0 *= dec8(g1, 0); p1 *= dec8(g1, 1); p2 *= dec8(g1, 2); p3 *= dec8(g1, 3);
        p0 *= dec8(g2, 0); p1 *= dec8(g2, 1); p2 *= dec8(g2, 2); p3 *= dec8(g2, 3);
        p0 *= dec8(g3, 0); p1 *= dec8(g3, 1); p2 *= dec8(g3, 2); p3 *= dec8(g3, 3);
        p0 *= dec8(g4, 0); p1 *= dec8(g4, 1); p2 *= dec8(g4, 2); p3 *= dec8(g4, 3);
        p0 *= dec8(g5, 0); p1 *= dec8(g5, 1); p2 *= dec8(g5, 2); p3 *= dec8(g5, 3);
        p0 *= dec8(g6, 0); p1 *= dec8(g6, 1); p2 *= dec8(g6, 2); p3 *= dec8(g6, 3);
        p0 *= dec8(g7, 0); p1 *= dec8(g7, 1); p2 *= dec8(g7, 2); p3 *= dec8(g7, 3);
        acc += bce_log2(p0, syn0[m]);
        acc += bce_log2(p1, syn1[m]);
        acc += bce_log2(p2, syn2[m]);
        acc += bce_log2(p3, syn3[m]);
        ++cnt;
    }
    float sum = 0.5f * LN2_ * (4.0f * (float)cnt - acc);   // BETA = 0.5

    // Obs part: only h==0 blocks (once per row). Wave-uniform row select.
    if (h == 0 && tid < 256) {
        const int row = tid >> 6;          // 0..3, wave-uniform
        const int k   = (tid >> 3) & 7;
        const int seg = tid & 7;
        const int* oc = obs_cols + k * OBS_W_ + seg * 25;
        const int sh  = 8 * row;
        float pr = 1.0f;
        #pragma unroll 5
        for (int w = 0; w < 25; ++w) {
            unsigned int gw = t8[oc[w]];
            float u = (float)((gw >> sh) & 0xffu);
            pr *= fmaf(u, QINV, QBIASINV);
        }
        #pragma unroll
        for (int off = 1; off < 8; off <<= 1) pr *= __shfl_xor(pr, off, 64);
        if (seg == 0) {
            float y = observables[(size_t)(b0 + row) * K_ + k];
            sum += 0.5f * LN2_ * (1.0f - bce_log2(pr, y));  // 1-BETA
        }
    }

    // Block reduction.
    for (int off = 32; off > 0; off >>= 1) sum += __shfl_down(sum, off, 64);
    const int lane = tid & 63, wv = tid >> 6;
    if (lane == 0) red[wv] = sum;
    __syncthreads();
    if (tid == 0) {
        float tot = 0.0f;
        #pragma unroll
        for (int i = 0; i < TPB / 64; ++i) tot += red[i];
        if (ATOMIC) atomicAdd(part, tot * (1.0f / (float)B_));
        else        part[blockIdx.x] = tot;
    }
}

__global__ __launch_bounds__(256) void decode_loss_reduce(
    const float* __restrict__ part, float* __restrict__ out, int n)
{
    __shared__ float red[4];
    const int tid = threadIdx.x;
    float s = 0.0f;
    for (int i = tid; i < n; i += 256) s += part[i];
    for (int off = 32; off > 0; off >>= 1) s += __shfl_down(s, off, 64);
    const int lane = tid & 63, wv = tid >> 6;
    if (lane == 0) red[wv] = s;
    __syncthreads();
    if (tid == 0) out[0] = (red[0] + red[1] + red[2] + red[3]) * (1.0f / (float)B_);
}

extern "C" void kernel_launch(void* const* d_in, const int* in_sizes, int n_in,
                              void* d_out, int out_size, void* d_ws, size_t ws_size,
                              hipStream_t stream) {
    const float* llrs        = (const float*)d_in[0];
    const float* syndromes   = (const float*)d_in[1];
    const float* observables = (const float*)d_in[2];
    const int*   chk_cols    = (const int*)d_in[3];
    const int*   obs_cols    = (const int*)d_in[4];
    float*       out         = (float*)d_out;

    const size_t lds_bytes = (size_t)N_ * 4;   // 80 000 B (4 rows x int8)
    const int    nblk      = 2 * (B_ / 4);     // 512: pair-split checks

    (void)hipFuncSetAttribute((const void*)decode_loss_q8<false>,
        hipFuncAttributeMaxDynamicSharedMemorySize, (int)lds_bytes);
    (void)hipFuncSetAttribute((const void*)decode_loss_q8<true>,
        hipFuncAttributeMaxDynamicSharedMemorySize, (int)lds_bytes);

    if (ws_size >= (size_t)nblk * sizeof(float)) {
        float* part = (float*)d_ws;
        decode_loss_q8<false><<<nblk, TPB, lds_bytes, stream>>>(
            llrs, syndromes, observables, chk_cols, obs_cols, part);
        decode_loss_reduce<<<1, 256, 0, stream>>>(part, out, nblk);
    } else {
        hipMemsetAsync(out, 0, sizeof(float), stream);
        decode_loss_q8<true><<<nblk, TPB, lds_bytes, stream>>>(
            llrs, syndromes, observables, chk_cols, obs_cols, out);
    }
}

// Round 8
// 29.434 us; speedup vs baseline: 1.3060x; 1.3060x over previous
//
#include <hip/hip_runtime.h>

#define B_ 1024
#define N_ 20000
#define M_ 10000
#define K_ 8
#define OBS_W_ 200
#define TPB 1024

constexpr float EPS_   = 1e-6f;
constexpr float LN2_   = 0.69314718055994530942f;
constexpr float LOG2E_ = 1.4426950408889634f;
constexpr float QSCALE   = 127.0f;
constexpr float QINV     = 1.0f / 127.0f;
constexpr float QBIASINV = -128.0f / 127.0f;

// tanh(x/2) = 1 - 2/(exp(x)+1), via hardware v_exp_f32 / v_rcp_f32.
__device__ __forceinline__ float tanh_half_fast(float x) {
    float e = __builtin_amdgcn_exp2f(x * LOG2E_);
    return 1.0f - 2.0f * __builtin_amdgcn_rcpf(e + 1.0f);
}

__device__ __forceinline__ float bce_log2(float p, float y) {
    // ln2 - log1p((1-2y)*p) accumulated as log2; caller applies LN2*(cnt-acc).
    p = fminf(fmaxf(p, -1.0f + EPS_), 1.0f - EPS_);
    float w = fmaf(1.0f - 2.0f * y, p, 1.0f);
    return __builtin_amdgcn_logf(w);   // log2(w)
}

// int8 symmetric quant: q = rint(t*127)+128 in [1,255]; t in (-1,1).
__device__ __forceinline__ unsigned int quant8(float t) {
    return (unsigned int)(int)rintf(fmaf(t, QSCALE, 128.0f));
}
__device__ __forceinline__ unsigned int pack4_q8(float a, float b, float c, float d) {
    return quant8(a) | (quant8(b) << 8) | (quant8(c) << 16) | (quant8(d) << 24);
}
// decode byte k of word g -> float t; lowers to v_cvt_f32_ubyteN + v_fma.
__device__ __forceinline__ float dec8(unsigned int g, int k) {
    float u = (float)((g >> (8 * k)) & 0xffu);
    return fmaf(u, QINV, QBIASINV);
}

// ---- int8: 4 rows per uint32, 80 KB LDS, grid 256, stage-once (no split) ---
template <bool ATOMIC>
__global__ __launch_bounds__(TPB) void decode_loss_q8(
    const float* __restrict__ llrs,
    const float* __restrict__ syndromes,
    const float* __restrict__ observables,
    const int*   __restrict__ chk_cols,
    const int*   __restrict__ obs_cols,
    float* __restrict__ part)
{
    extern __shared__ char smem_raw[];
    unsigned int* t8 = reinterpret_cast<unsigned int*>(smem_raw);
    __shared__ float red[TPB / 64];

    const int b0  = 4 * blockIdx.x;
    const int tid = threadIdx.x;

    // Stage: t8[n] = bytes {q(r0), q(r1), q(r2), q(r3)}.
    const float4* r0 = reinterpret_cast<const float4*>(llrs + (size_t)(b0 + 0) * N_);
    const float4* r1 = reinterpret_cast<const float4*>(llrs + (size_t)(b0 + 1) * N_);
    const float4* r2 = reinterpret_cast<const float4*>(llrs + (size_t)(b0 + 2) * N_);
    const float4* r3 = reinterpret_cast<const float4*>(llrs + (size_t)(b0 + 3) * N_);
    for (int i = tid; i < N_ / 4; i += TPB) {
        float4 a = r0[i], b = r1[i], c = r2[i], d = r3[i];
        int4 w;
        w.x = (int)pack4_q8(tanh_half_fast(a.x), tanh_half_fast(b.x),
                            tanh_half_fast(c.x), tanh_half_fast(d.x));
        w.y = (int)pack4_q8(tanh_half_fast(a.y), tanh_half_fast(b.y),
                            tanh_half_fast(c.y), tanh_half_fast(d.y));
        w.z = (int)pack4_q8(tanh_half_fast(a.z), tanh_half_fast(b.z),
                            tanh_half_fast(c.z), tanh_half_fast(d.z));
        w.w = (int)pack4_q8(tanh_half_fast(a.w), tanh_half_fast(b.w),
                            tanh_half_fast(c.w), tanh_half_fast(d.w));
        *reinterpret_cast<int4*>(&t8[4 * i]) = w;
    }
    __syncthreads();

    // Check part: full M per block, 4 rows per gather word.
    float acc = 0.0f;
    int   cnt = 0;
    const float* syn0 = syndromes + (size_t)(b0 + 0) * M_;
    const float* syn1 = syndromes + (size_t)(b0 + 1) * M_;
    const float* syn2 = syndromes + (size_t)(b0 + 2) * M_;
    const float* syn3 = syndromes + (size_t)(b0 + 3) * M_;
    const int4*  cc   = reinterpret_cast<const int4*>(chk_cols);
    for (int m = tid; m < M_; m += TPB) {
        int4 c0 = cc[2 * m];
        int4 c1 = cc[2 * m + 1];
        unsigned int g0 = t8[c0.x], g1 = t8[c0.y], g2 = t8[c0.z], g3 = t8[c0.w];
        unsigned int g4 = t8[c1.x], g5 = t8[c1.y], g6 = t8[c1.z], g7 = t8[c1.w];
        float p0 = dec8(g0, 0), p1 = dec8(g0, 1), p2 = dec8(g0, 2), p3 = dec8(g0, 3);
        p0 *= dec8(g1, 0); p1 *= dec8(g1, 1); p2 *= dec8(g1, 2); p3 *= dec8(g1, 3);
        p0 *= dec8(g2, 0); p1 *= dec8(g2, 1); p2 *= dec8(g2, 2); p3 *= dec8(g2, 3);
        p0 *= dec8(g3, 0); p1 *= dec8(g3, 1); p2 *= dec8(g3, 2); p3 *= dec8(g3, 3);
        p0 *= dec8(g4, 0); p1 *= dec8(g4, 1); p2 *= dec8(g4, 2); p3 *= dec8(g4, 3);
        p0 *= dec8(g5, 0); p1 *= dec8(g5, 1); p2 *= dec8(g5, 2); p3 *= dec8(g5, 3);
        p0 *= dec8(g6, 0); p1 *= dec8(g6, 1); p2 *= dec8(g6, 2); p3 *= dec8(g6, 3);
        p0 *= dec8(g7, 0); p1 *= dec8(g7, 1); p2 *= dec8(g7, 2); p3 *= dec8(g7, 3);
        acc += bce_log2(p0, syn0[m]);
        acc += bce_log2(p1, syn1[m]);
        acc += bce_log2(p2, syn2[m]);
        acc += bce_log2(p3, syn3[m]);
        ++cnt;
    }
    float sum = 0.5f * LN2_ * (4.0f * (float)cnt - acc);   // BETA = 0.5

    // Obs part: 4 waves; wave=row, 8 lanes per k, 25 elems per lane.
    if (tid < 256) {
        const int row = tid >> 6;          // 0..3, wave-uniform
        const int k   = (tid >> 3) & 7;
        const int seg = tid & 7;
        const int* oc = obs_cols + k * OBS_W_ + seg * 25;
        const int sh  = 8 * row;
        float pr = 1.0f;
        #pragma unroll 5
        for (int w = 0; w < 25; ++w) {
            unsigned int gw = t8[oc[w]];
            float u = (float)((gw >> sh) & 0xffu);
            pr *= fmaf(u, QINV, QBIASINV);
        }
        #pragma unroll
        for (int off = 1; off < 8; off <<= 1) pr *= __shfl_xor(pr, off, 64);
        if (seg == 0) {
            float y = observables[(size_t)(b0 + row) * K_ + k];
            sum += 0.5f * LN2_ * (1.0f - bce_log2(pr, y));  // 1-BETA
        }
    }

    // Block reduction.
    for (int off = 32; off > 0; off >>= 1) sum += __shfl_down(sum, off, 64);
    const int lane = tid & 63, wv = tid >> 6;
    if (lane == 0) red[wv] = sum;
    __syncthreads();
    if (tid == 0) {
        float tot = 0.0f;
        #pragma unroll
        for (int i = 0; i < TPB / 64; ++i) tot += red[i];
        if (ATOMIC) atomicAdd(part, tot * (1.0f / (float)B_));
        else        part[blockIdx.x] = tot;
    }
}

__global__ __launch_bounds__(256) void decode_loss_reduce(
    const float* __restrict__ part, float* __restrict__ out, int n)
{
    __shared__ float red[4];
    const int tid = threadIdx.x;
    float s = 0.0f;
    for (int i = tid; i < n; i += 256) s += part[i];
    for (int off = 32; off > 0; off >>= 1) s += __shfl_down(s, off, 64);
    const int lane = tid & 63, wv = tid >> 6;
    if (lane == 0) red[wv] = s;
    __syncthreads();
    if (tid == 0) out[0] = (red[0] + red[1] + red[2] + red[3]) * (1.0f / (float)B_);
}

extern "C" void kernel_launch(void* const* d_in, const int* in_sizes, int n_in,
                              void* d_out, int out_size, void* d_ws, size_t ws_size,
                              hipStream_t stream) {
    const float* llrs        = (const float*)d_in[0];
    const float* syndromes   = (const float*)d_in[1];
    const float* observables = (const float*)d_in[2];
    const int*   chk_cols    = (const int*)d_in[3];
    const int*   obs_cols    = (const int*)d_in[4];
    float*       out         = (float*)d_out;

    const size_t lds_bytes = (size_t)N_ * 4;   // 80 000 B (4 rows x int8)
    const int    nblk      = B_ / 4;           // 256, stage-once

    (void)hipFuncSetAttribute((const void*)decode_loss_q8<false>,
        hipFuncAttributeMaxDynamicSharedMemorySize, (int)lds_bytes);
    (void)hipFuncSetAttribute((const void*)decode_loss_q8<true>,
        hipFuncAttributeMaxDynamicSharedMemorySize, (int)lds_bytes);

    if (ws_size >= (size_t)nblk * sizeof(float)) {
        float* part = (float*)d_ws;
        decode_loss_q8<false><<<nblk, TPB, lds_bytes, stream>>>(
            llrs, syndromes, observables, chk_cols, obs_cols, part);
        decode_loss_reduce<<<1, 256, 0, stream>>>(part, out, nblk);
    } else {
        hipMemsetAsync(out, 0, sizeof(float), stream);
        decode_loss_q8<true><<<nblk, TPB, lds_bytes, stream>>>(
            llrs, syndromes, observables, chk_cols, obs_cols, out);
    }
}

// Round 9
// 29.230 us; speedup vs baseline: 1.3151x; 1.0070x over previous
//
#include <hip/hip_runtime.h>

#define B_ 1024
#define N_ 20000
#define M_ 10000
#define K_ 8
#define OBS_W_ 200
#define TPB 1024
#define NV4 (N_ / 4)   // 5000 float4 per row

constexpr float EPS_   = 1e-6f;
constexpr float LN2_   = 0.69314718055994530942f;
constexpr float LOG2E_ = 1.4426950408889634f;

typedef _Float16 f16x2 __attribute__((ext_vector_type(2)));
typedef _Float16 f16x8 __attribute__((ext_vector_type(8)));

// tanh(x/2) = 1 - 2/(exp(x)+1), via hardware v_exp_f32 / v_rcp_f32.
__device__ __forceinline__ float tanh_half_fast(float x) {
    float e = __builtin_amdgcn_exp2f(x * LOG2E_);
    return 1.0f - 2.0f * __builtin_amdgcn_rcpf(e + 1.0f);
}

__device__ __forceinline__ float bce_log2(float p, float y) {
    // ln2 - log1p((1-2y)*p) accumulated as log2; caller applies LN2*(n-acc).
    p = fminf(fmaxf(p, -1.0f + EPS_), 1.0f - EPS_);
    float w = fmaf(1.0f - 2.0f * y, p, 1.0f);
    return __builtin_amdgcn_logf(w);   // log2(w)
}

// One check row m against a 2-row f16x2 buffer; accumulates 2 log2 terms.
__device__ __forceinline__ void do_check2(const f16x2* __restrict__ t2,
                                          const float* __restrict__ synA,
                                          const float* __restrict__ synB,
                                          const int4* __restrict__ cc,
                                          int m, float& acc, int& nterm) {
    int4 c0 = cc[2 * m];
    int4 c1 = cc[2 * m + 1];
    f16x2 g0 = t2[c0.x], g1 = t2[c0.y], g2 = t2[c0.z], g3 = t2[c0.w];
    f16x2 g4 = t2[c1.x], g5 = t2[c1.y], g6 = t2[c1.z], g7 = t2[c1.w];
    f16x2 p  = ((g0 * g1) * (g2 * g3)) * ((g4 * g5) * (g6 * g7));
    acc += bce_log2((float)p[0], synA[m]);
    acc += bce_log2((float)p[1], synB[m]);
    nterm += 2;
}

__device__ __forceinline__ f16x8 pack2(float4 a, float4 c) {
    f16x8 v;
    v[0] = (_Float16)tanh_half_fast(a.x); v[1] = (_Float16)tanh_half_fast(c.x);
    v[2] = (_Float16)tanh_half_fast(a.y); v[3] = (_Float16)tanh_half_fast(c.y);
    v[4] = (_Float16)tanh_half_fast(a.z); v[5] = (_Float16)tanh_half_fast(c.z);
    v[6] = (_Float16)tanh_half_fast(a.w); v[7] = (_Float16)tanh_half_fast(c.w);
    return v;
}

// 4 rows per block as two 2-row groups, double-buffered 2x80KB LDS pipeline:
//   S0 -> sync -> [gather g0 || stage S1] -> sync -> gather g1 -> obs -> reduce
template <bool ATOMIC>
__global__ __launch_bounds__(TPB) void decode_loss_pipe(
    const float* __restrict__ llrs,
    const float* __restrict__ syndromes,
    const float* __restrict__ observables,
    const int*   __restrict__ chk_cols,
    const int*   __restrict__ obs_cols,
    float* __restrict__ part)
{
    extern __shared__ char smem_raw[];
    f16x2* t2a = reinterpret_cast<f16x2*>(smem_raw);          // rows b0, b0+1
    f16x2* t2b = t2a + N_;                                    // rows b0+2, b0+3
    __shared__ float red[TPB / 64];

    const int b0  = 4 * blockIdx.x;
    const int tid = threadIdx.x;

    const float4* r0 = reinterpret_cast<const float4*>(llrs + (size_t)(b0 + 0) * N_);
    const float4* r1 = reinterpret_cast<const float4*>(llrs + (size_t)(b0 + 1) * N_);
    const float4* r2 = reinterpret_cast<const float4*>(llrs + (size_t)(b0 + 2) * N_);
    const float4* r3 = reinterpret_cast<const float4*>(llrs + (size_t)(b0 + 3) * N_);

    // ---- S0: stage rows b0, b0+1 into buf A ----
    for (int i = tid; i < NV4; i += TPB) {
        *reinterpret_cast<f16x8*>(&t2a[4 * i]) = pack2(r0[i], r1[i]);
    }
    __syncthreads();

    const float* syn0 = syndromes + (size_t)(b0 + 0) * M_;
    const float* syn1 = syndromes + (size_t)(b0 + 1) * M_;
    const float* syn2 = syndromes + (size_t)(b0 + 2) * M_;
    const float* syn3 = syndromes + (size_t)(b0 + 3) * M_;
    const int4*  cc   = reinterpret_cast<const int4*>(chk_cols);

    float acc   = 0.0f;
    int   nterm = 0;

    // ---- pipeline: gather g0 on buf A while staging rows b0+2,b0+3 -> buf B.
    // 5 steps x (issue 2 float4 loads; 2 check iters; tanh+pack+write).
    #pragma unroll 1
    for (int it = 0; it < 5; ++it) {
        const int  i  = tid + it * TPB;
        const bool iv = (i < NV4);
        float4 a, c;
        if (iv) { a = r2[i]; c = r3[i]; }           // loads in flight...
        const int m0 = tid + (2 * it) * TPB;        // ...hidden under gathers
        const int m1 = m0 + TPB;
        if (m0 < M_) do_check2(t2a, syn0, syn1, cc, m0, acc, nterm);
        if (m1 < M_) do_check2(t2a, syn0, syn1, cc, m1, acc, nterm);
        if (iv) *reinterpret_cast<f16x8*>(&t2b[4 * i]) = pack2(a, c);
    }
    __syncthreads();

    // ---- gather g1 on buf B ----
    for (int m = tid; m < M_; m += TPB) {
        do_check2(t2b, syn2, syn3, cc, m, acc, nterm);
    }

    float sum = 0.5f * LN2_ * ((float)nterm - acc);   // BETA = 0.5

    // ---- obs part: 4 waves; wave=row; rows 0,1 from buf A, rows 2,3 buf B.
    if (tid < 256) {
        const int row  = tid >> 6;                    // 0..3, wave-uniform
        const int k    = (tid >> 3) & 7;
        const int seg  = tid & 7;
        const f16x2* tb   = (row < 2) ? t2a : t2b;
        const int    comp = row & 1;
        const int*   oc   = obs_cols + k * OBS_W_ + seg * 25;
        float pr = 1.0f;
        #pragma unroll 5
        for (int w = 0; w < 25; ++w) pr *= (float)tb[oc[w]][comp];
        #pragma unroll
        for (int off = 1; off < 8; off <<= 1) pr *= __shfl_xor(pr, off, 64);
        if (seg == 0) {
            float y = observables[(size_t)(b0 + row) * K_ + k];
            sum += 0.5f * LN2_ * (1.0f - bce_log2(pr, y));   // 1-BETA
        }
    }

    // ---- block reduction ----
    for (int off = 32; off > 0; off >>= 1) sum += __shfl_down(sum, off, 64);
    const int lane = tid & 63, wv = tid >> 6;
    if (lane == 0) red[wv] = sum;
    __syncthreads();
    if (tid == 0) {
        float tot = 0.0f;
        #pragma unroll
        for (int i = 0; i < TPB / 64; ++i) tot += red[i];
        if (ATOMIC) atomicAdd(part, tot * (1.0f / (float)B_));
        else        part[blockIdx.x] = tot;
    }
}

__global__ __launch_bounds__(256) void decode_loss_reduce(
    const float* __restrict__ part, float* __restrict__ out, int n)
{
    __shared__ float red[4];
    const int tid = threadIdx.x;
    float s = 0.0f;
    for (int i = tid; i < n; i += 256) s += part[i];
    for (int off = 32; off > 0; off >>= 1) s += __shfl_down(s, off, 64);
    const int lane = tid & 63, wv = tid >> 6;
    if (lane == 0) red[wv] = s;
    __syncthreads();
    if (tid == 0) out[0] = (red[0] + red[1] + red[2] + red[3]) * (1.0f / (float)B_);
}

extern "C" void kernel_launch(void* const* d_in, const int* in_sizes, int n_in,
                              void* d_out, int out_size, void* d_ws, size_t ws_size,
                              hipStream_t stream) {
    const float* llrs        = (const float*)d_in[0];
    const float* syndromes   = (const float*)d_in[1];
    const float* observables = (const float*)d_in[2];
    const int*   chk_cols    = (const int*)d_in[3];
    const int*   obs_cols    = (const int*)d_in[4];
    float*       out         = (float*)d_out;

    const size_t lds_bytes = (size_t)N_ * 2 * sizeof(f16x2);   // 160 000 B
    const int    nblk      = B_ / 4;                           // 256

    (void)hipFuncSetAttribute((const void*)decode_loss_pipe<false>,
        hipFuncAttributeMaxDynamicSharedMemorySize, (int)lds_bytes);
    (void)hipFuncSetAttribute((const void*)decode_loss_pipe<true>,
        hipFuncAttributeMaxDynamicSharedMemorySize, (int)lds_bytes);

    if (ws_size >= (size_t)nblk * sizeof(float)) {
        float* part = (float*)d_ws;
        decode_loss_pipe<false><<<nblk, TPB, lds_bytes, stream>>>(
            llrs, syndromes, observables, chk_cols, obs_cols, part);
        decode_loss_reduce<<<1, 256, 0, stream>>>(part, out, nblk);
    } else {
        hipMemsetAsync(out, 0, sizeof(float), stream);
        decode_loss_pipe<true><<<nblk, TPB, lds_bytes, stream>>>(
            llrs, syndromes, observables, chk_cols, obs_cols, out);
    }
}